// Round 12
// baseline (740.231 us; speedup 1.0000x reference)
//
#include <hip/hip_runtime.h>
#include <hip/hip_bf16.h>

typedef unsigned short u16;
typedef __attribute__((ext_vector_type(8))) short short8;
typedef __attribute__((ext_vector_type(4))) float f32x4;
typedef __attribute__((ext_vector_type(8))) unsigned short ushort8v;

#define NVOX 200000
#define NVP  200064
#define NOFF 27
#define NBLK 1563

__device__ __forceinline__ u16 f2bf(float f) {
    __hip_bfloat16 h = __float2bfloat16(f);
    return *reinterpret_cast<u16*>(&h);
}
__device__ __forceinline__ float bf2f(u16 u) {
    union { unsigned int i; float f; } v;
    v.i = ((unsigned int)u) << 16;
    return v.f;
}

#define GLOAD_LDS16(g, l)                                                     \
    __builtin_amdgcn_global_load_lds(                                         \
        (const __attribute__((address_space(1))) unsigned int*)(g),           \
        (__attribute__((address_space(3))) unsigned int*)(l), 16, 0, 0)

__device__ __forceinline__ int gld32(const int* p) {
    int r;
    asm volatile("global_load_dword %0, %1, off" : "=v"(r) : "v"(p) : "memory");
    return r;
}
__device__ __forceinline__ uint4 dsr128(const u16* p) {
    uint4 r;
    asm volatile("ds_read_b128 %0, %1"
                 : "=v"(r)
                 : "v"((const __attribute__((address_space(3))) uint4*)p));
    return r;
}
__device__ __forceinline__ short8 as_s8(uint4 v) {
    union { uint4 u; short8 s; } c; c.u = v; return c.s;
}
#define S_WAIT_VM(n) asm volatile("s_waitcnt vmcnt(" #n ")" ::: "memory")
#define S_WAIT_LG(n) asm volatile("s_waitcnt lgkmcnt(" #n ")" ::: "memory")
#define SBAR0()      __builtin_amdgcn_sched_barrier(0)

// ---------------------------------------------------------------------------
// prep: cast x -> bf16; repack W1/W2 fragment-major with PADDED per-step
// strides (conv1: 2560 chunks/step, conv2: 1536 chunks/half-step) so the
// conv W-stage loop has exact per-thread counts; zero page.
// ---------------------------------------------------------------------------
__global__ __launch_bounds__(256) void prep_kernel(
    const float* __restrict__ x, const float* __restrict__ W1,
    const float* __restrict__ W2, u16* __restrict__ xb,
    u16* __restrict__ w1t, u16* __restrict__ w2t, float* __restrict__ zbuf)
{
    const int XV = NVOX * 96 / 4;     // 4,800,000 vec4 cast jobs
    const int WC = 62208;             // W chunk jobs per conv (27*36*64)
    int t = blockIdx.x * 256 + threadIdx.x;
    if (blockIdx.x == 0 && threadIdx.x < 64) zbuf[threadIdx.x] = 0.f;
    if (t < XV) {
        float4 v = *(const float4*)(x + (size_t)t * 4);
        ushort4 o;
        o.x = f2bf(v.x); o.y = f2bf(v.y); o.z = f2bf(v.z); o.w = f2bf(v.w);
        *(ushort4*)(xb + (size_t)t * 4) = o;
    } else if (t < XV + WC) {
        int j = t - XV;
        int lane = j & 63, rest = j >> 6;
        int nco = rest % 12, rest2 = rest / 12;
        int ks = rest2 % 3, off = rest2 / 3;
        int co = nco * 16 + (lane & 15);
        int kb = ks * 32 + (lane >> 4) * 8;
        const float* src = W1 + (size_t)off * 18432 + (size_t)kb * 192 + co;
        ushort8v ov;
#pragma unroll
        for (int jj = 0; jj < 8; ++jj) ov[jj] = f2bf(src[(size_t)jj * 192]);
        *(ushort8v*)(w1t + (size_t)off * 20480 + (ks * 12 + nco) * 512 + lane * 8) = ov;
    } else if (t < XV + 2 * WC) {
        int j = t - XV - WC;
        int lane = j & 63, rest = j >> 6;
        int nco = rest % 6, rest2 = rest / 6;
        int ks = rest2 % 3, rest3 = rest2 / 3;
        int hf = rest3 % 2, off = rest3 / 2;
        int co = nco * 16 + (lane & 15);
        int kb = hf * 96 + ks * 32 + (lane >> 4) * 8;
        const float* src = W2 + (size_t)off * 18432 + (size_t)kb * 96 + co;
        ushort8v ov;
#pragma unroll
        for (int jj = 0; jj < 8; ++jj) ov[jj] = f2bf(src[(size_t)jj * 96]);
        *(ushort8v*)(w2t + (size_t)(off * 2 + hf) * 12288 +
                     (ks * 6 + nco) * 512 + lane * 8) = ov;
    }
}

// ---------------------------------------------------------------------------
// lsrc precompute: lsrcG[off][row] = mask>0 ? idx : -1  (rows padded to NVP)
// ---------------------------------------------------------------------------
__global__ __launch_bounds__(256) void lsrc_kernel(
    const int* __restrict__ idxp, const int* __restrict__ mskp,
    int* __restrict__ lsrcG)
{
    int r = blockIdx.x * 256 + threadIdx.x;
    int o = blockIdx.y;
    if (r < NVP) {
        int v = -1;
        if (r < NVOX) {
            if (mskp[(size_t)o * NVOX + r] > 0) v = idxp[(size_t)o * NVOX + r];
        }
        lsrcG[(size_t)o * NVP + r] = v;
    }
}

// ---------------------------------------------------------------------------
// conv: explicit-GEMM sparse conv, bf16 MFMA, f32 accum.
//   W staged per step into an LDS double-buffer via global_load_lds (shared
//   across waves -> kills the 2x/4x per-wave W L2-read duplication, the
//   largest identified pipe consumer).  A: 3-buffer gather pipeline
//   (zbuf fixed-count).  Per iter: stageW(s+1), sv(s+3), gather(s+2),
//   vmcnt(3) [keeps gathers in flight across the raw barrier; every LDS
//   write retires >=1 barrier before its readers], MFMA (lgkm-counted),
//   s_barrier.  1 block/CU (152/120 KB LDS), VGPR cap 256 -> no spill.
// ---------------------------------------------------------------------------
template<int COUT, int WN, int HFDIV>
__global__ __launch_bounds__(512, 2) void conv_mfma(
    const u16* __restrict__ xb, const int* __restrict__ lsrcG,
    const u16* __restrict__ Wt, const float* __restrict__ zbuf,
    u16* __restrict__ hout, float* __restrict__ part)
{
    constexpr int CIN  = 96 * HFDIV;
    constexpr int WM   = 8 / WN;
    constexpr int FM   = 128 / (WM * 16);   // 4 (conv1) / 2 (conv2)
    constexpr int FN   = COUT / (WN * 16);  // 3 both
    constexpr int NCO  = COUT / 16;
    constexpr int SG   = NOFF * HFDIV;      // 27 / 54
    constexpr int BUFU = 12288;             // u16 per A buffer (24 KB)
    constexpr int WPAD = (COUT == 192) ? 2560 : 1536;  // chunks per W step
    constexpr int WCH  = WPAD / 512;        // W-stage instrs per thread (5/3)
    constexpr int WBUFU = WPAD * 8;         // u16 per W buffer

    __shared__ u16 ldsA[3 * BUFU];          // 73728 B
    __shared__ u16 ldsW[2 * WBUFU];         // 81920 B (conv1) / 49152 (conv2)

    const int tid  = threadIdx.x;
    const int row0 = blockIdx.x * 128;
    const int lane = tid & 63;
    const int wid  = tid >> 6;
    const int wm   = wid / WN;
    const int wn   = wid % WN;
    const int lr   = lane & 15;
    const int lk   = lane >> 4;

    // A staging: thread stages row wid*16+(lane&15), chunks 4*it+(lane>>4)
    const int rStage = wid * 16 + (lane & 15);
    const int cBase  = (lane >> 4) * 8;
    const int ldsWaveBase = wid * 512;      // u16; HW adds lane*16B
    const int wStageBase  = (tid & ~63) * 8;

    int rdBase[FM];
#pragma unroll
    for (int m = 0; m < FM; ++m)
        rdBase[m] = (wm * FM + m) * 512 + lr * 8 + lk * 128;
    const int wfBase = (wn * FN) * 512 + lane * 8;
    const int* lsp = lsrcG + row0 + rStage;

    f32x4 acc[FM][FN];
#pragma unroll
    for (int m = 0; m < FM; ++m)
#pragma unroll
        for (int n = 0; n < FN; ++n)
            acc[m][n] = (f32x4){0.f, 0.f, 0.f, 0.f};

    auto hfOf = [&](int s) -> int { return (HFDIV == 1) ? 0 : (s & 1); };
    auto svAddr = [&](int s) -> const int* {
        int idx2 = (s < SG) ? s : (SG - 1);
        int offIdx = (HFDIV == 1) ? idx2 : (idx2 >> 1);
        return lsp + (size_t)offIdx * NVP;
    };
    auto gatherTo = [&](int sv, int hf, int bsel) {
        const u16* g = (sv >= 0)
            ? (xb + (size_t)sv * CIN + hf * 96 + cBase)
            : ((const u16*)zbuf + cBase);
#pragma unroll
        for (int it = 0; it < 3; ++it)
            GLOAD_LDS16(g + it * 32,
                        ldsA + bsel * BUFU + it * 4096 + ldsWaveBase);
    };
    auto stageW = [&](int s, int wsel) {
        const u16* src = Wt + (size_t)s * WBUFU + (size_t)tid * 8;
        u16* dst = ldsW + wsel * WBUFU + wStageBase;
#pragma unroll
        for (int it = 0; it < WCH; ++it)
            GLOAD_LDS16(src + it * 4096, dst + it * 4096);
    };
    auto mfmaPhase = [&](int cur, int wsel) {
        const u16* abuf = ldsA + cur * BUFU;
        const u16* wbuf = ldsW + wsel * WBUFU + wfBase;
        uint4 a0[FM], a1[FM], w0[FN], w1[FN];
#pragma unroll
        for (int n = 0; n < FN; ++n) w0[n] = dsr128(wbuf + n * 512);
#pragma unroll
        for (int m = 0; m < FM; ++m) a0[m] = dsr128(abuf + rdBase[m]);
#pragma unroll
        for (int n = 0; n < FN; ++n) w1[n] = dsr128(wbuf + (NCO + n) * 512);
#pragma unroll
        for (int m = 0; m < FM; ++m) a1[m] = dsr128(abuf + 4096 + rdBase[m]);
        if constexpr (FM == 4) S_WAIT_LG(7); else S_WAIT_LG(5);
        SBAR0();
#pragma unroll
        for (int m = 0; m < FM; ++m)
#pragma unroll
            for (int n = 0; n < FN; ++n)
                acc[m][n] = __builtin_amdgcn_mfma_f32_16x16x32_bf16(
                    as_s8(a0[m]), as_s8(w0[n]), acc[m][n], 0, 0, 0);
#pragma unroll
        for (int n = 0; n < FN; ++n) w0[n] = dsr128(wbuf + (2 * NCO + n) * 512);
#pragma unroll
        for (int m = 0; m < FM; ++m) a0[m] = dsr128(abuf + 8192 + rdBase[m]);
        if constexpr (FM == 4) S_WAIT_LG(7); else S_WAIT_LG(5);
        SBAR0();
#pragma unroll
        for (int m = 0; m < FM; ++m)
#pragma unroll
            for (int n = 0; n < FN; ++n)
                acc[m][n] = __builtin_amdgcn_mfma_f32_16x16x32_bf16(
                    as_s8(a1[m]), as_s8(w1[n]), acc[m][n], 0, 0, 0);
        S_WAIT_LG(0);
        SBAR0();
#pragma unroll
        for (int m = 0; m < FM; ++m)
#pragma unroll
            for (int n = 0; n < FN; ++n)
                acc[m][n] = __builtin_amdgcn_mfma_f32_16x16x32_bf16(
                    as_s8(a0[m]), as_s8(w0[n]), acc[m][n], 0, 0, 0);
    };

    // ---- prologue: sv(0..2); stage W(0); gather(0),(1); retire all but g(1)
    int svC;
    {
        int sv0 = gld32(svAddr(0));
        int sv1 = gld32(svAddr(1));
        int sv2 = gld32(svAddr(2));
        S_WAIT_VM(0); SBAR0();
        stageW(0, 0);
        gatherTo(sv0, hfOf(0), 0);
        gatherTo(sv1, hfOf(1), 1);
        svC = sv2;
        S_WAIT_VM(3); SBAR0();          // W(0), g(0) retired; g(1) in flight
        __builtin_amdgcn_s_barrier();
        SBAR0();
    }

    int cur = 0, nxt2 = 2;
    // ---- steady loop: s = 0 .. SG-3 ----
#pragma unroll 1
    for (int s = 0; s < SG - 2; ++s) {
        stageW(s + 1, (s + 1) & 1);             // WCH gload_lds
        int svN = gld32(svAddr(s + 3));         // 1
        gatherTo(svC, hfOf(s + 2), nxt2);       // 3 gload_lds (newest)
        SBAR0();
        S_WAIT_VM(3); SBAR0();                  // keep only g(s+2) in flight
        mfmaPhase(cur, s & 1);
        SBAR0();
        __builtin_amdgcn_s_barrier();           // raw: no vmem drain
        SBAR0();
        svC = svN;
        cur  = (cur == 2)  ? 0 : cur + 1;
        nxt2 = (nxt2 == 2) ? 0 : nxt2 + 1;
    }
    // ---- peeled s = SG-2 ----
    stageW(SG - 1, (SG - 1) & 1);
    SBAR0();
    S_WAIT_VM(0); SBAR0();
    mfmaPhase(cur, (SG - 2) & 1);
    SBAR0();
    __builtin_amdgcn_s_barrier();
    SBAR0();
    cur = (cur == 2) ? 0 : cur + 1;
    // ---- peeled s = SG-1 ----
    mfmaPhase(cur, (SG - 1) & 1);

    // ---- fused BN statsA: per-block partial sum/sumsq per channel ----
    __syncthreads();
    float* smf = (float*)ldsA;             // overlay [WM][COUT][2]
#pragma unroll
    for (int n = 0; n < FN; ++n) {
        float s1 = 0.f, s2 = 0.f;
#pragma unroll
        for (int m = 0; m < FM; ++m)
#pragma unroll
            for (int q = 0; q < 4; ++q) {
                float v = acc[m][n][q];
                s1 += v; s2 += v * v;
            }
        s1 += __shfl_xor(s1, 16); s1 += __shfl_xor(s1, 32);
        s2 += __shfl_xor(s2, 16); s2 += __shfl_xor(s2, 32);
        if (lane < 16) {
            int col = wn * (FN * 16) + n * 16 + lr;
            smf[(wm * COUT + col) * 2 + 0] = s1;
            smf[(wm * COUT + col) * 2 + 1] = s2;
        }
    }
    __syncthreads();
    if (tid < 2 * COUT) {
        int z = tid / COUT, cc = tid % COUT;
        float v = 0.f;
#pragma unroll
        for (int w = 0; w < WM; ++w) v += smf[(w * COUT + cc) * 2 + z];
        part[(size_t)blockIdx.x * (2 * COUT) + z * COUT + cc] = v;
    }

    // ---- store h (bf16): D layout col=lane&15, row=(lane>>4)*4+q ----
#pragma unroll
    for (int m = 0; m < FM; ++m) {
#pragma unroll
        for (int q = 0; q < 4; ++q) {
            int row = row0 + wm * (FM * 16) + m * 16 + lk * 4 + q;
            if (row < NVOX) {
#pragma unroll
                for (int n = 0; n < FN; ++n) {
                    int col = wn * (FN * 16) + n * 16 + lr;
                    hout[(size_t)row * COUT + col] = f2bf(acc[m][n][q]);
                }
            }
        }
    }
}

// ---------------------------------------------------------------------------
// BN stats reduce: sum partials over NBLK blocks, emit scale/shift
// ---------------------------------------------------------------------------
template<int COUT>
__global__ __launch_bounds__(256) void bn_statsB(
    const float* __restrict__ part, const float* __restrict__ g,
    const float* __restrict__ bv, float* __restrict__ ss)
{
    const int c = blockIdx.x;
    const int t = threadIdx.x;
    float s1 = 0.f, s2 = 0.f;
    for (int b = t; b < NBLK; b += 256) {
        s1 += part[(size_t)b * 2 * COUT + c];
        s2 += part[(size_t)b * 2 * COUT + COUT + c];
    }
#pragma unroll
    for (int d = 1; d < 64; d <<= 1) {
        s1 += __shfl_xor(s1, d);
        s2 += __shfl_xor(s2, d);
    }
    __shared__ float rs[8];
    int w = t >> 6;
    if ((t & 63) == 0) { rs[w] = s1; rs[4 + w] = s2; }
    __syncthreads();
    if (t == 0) {
        s1 = rs[0] + rs[1] + rs[2] + rs[3];
        s2 = rs[4] + rs[5] + rs[6] + rs[7];
        float mu  = s1 * (1.0f / NVOX);
        float var = s2 * (1.0f / NVOX) - mu * mu;
        float sc  = g[c] * rsqrtf(var + 1e-5f);
        ss[c] = sc;
        ss[COUT + c] = bv[c] - mu * sc;
    }
}

// ---------------------------------------------------------------------------
// apply BN + ReLU in place (bf16), vec8
// ---------------------------------------------------------------------------
template<int COUT>
__global__ __launch_bounds__(256) void bn_apply_relu(
    u16* __restrict__ h, const float* __restrict__ ss)
{
    int t = blockIdx.x * 256 + threadIdx.x;   // < NVOX*COUT/8
    int c0 = (t * 8) % COUT;
    ushort8v v = *(ushort8v*)(h + (size_t)t * 8);
#pragma unroll
    for (int j = 0; j < 8; ++j) {
        float f = bf2f(v[j]);
        f = fmaxf(f * ss[c0 + j] + ss[COUT + c0 + j], 0.f);
        v[j] = f2bf(f);
    }
    *(ushort8v*)(h + (size_t)t * 8) = v;
}

// ---------------------------------------------------------------------------
// final: out = relu(scale2*h2 + shift2 + x), f32 out, vec8
// ---------------------------------------------------------------------------
__global__ __launch_bounds__(256) void final_kernel(
    const u16* __restrict__ h2, const float* __restrict__ x,
    const float* __restrict__ ss, float* __restrict__ out)
{
    int t = blockIdx.x * 256 + threadIdx.x;   // < NVOX*96/8
    int c0 = (t * 8) % 96;
    ushort8v v = *(const ushort8v*)(h2 + (size_t)t * 8);
    float4 x0 = *(const float4*)(x + (size_t)t * 8);
    float4 x1 = *(const float4*)(x + (size_t)t * 8 + 4);
    float xs[8] = {x0.x, x0.y, x0.z, x0.w, x1.x, x1.y, x1.z, x1.w};
    float o[8];
#pragma unroll
    for (int j = 0; j < 8; ++j) {
        float f = bf2f(v[j]) * ss[c0 + j] + ss[96 + c0 + j] + xs[j];
        o[j] = fmaxf(f, 0.f);
    }
    *(float4*)(out + (size_t)t * 8)     = (float4){o[0], o[1], o[2], o[3]};
    *(float4*)(out + (size_t)t * 8 + 4) = (float4){o[4], o[5], o[6], o[7]};
}

// ---------------------------------------------------------------------------
extern "C" void kernel_launch(void* const* d_in, const int* in_sizes, int n_in,
                              void* d_out, int out_size, void* d_ws, size_t ws_size,
                              hipStream_t stream)
{
    const float* x    = (const float*)d_in[0];
    const int*   idx  = (const int*)d_in[1];
    const int*   mask = (const int*)d_in[2];
    const float* W1   = (const float*)d_in[3];
    const float* g1   = (const float*)d_in[4];
    const float* b1   = (const float*)d_in[5];
    const float* W2   = (const float*)d_in[6];
    const float* g2   = (const float*)d_in[7];
    const float* b2   = (const float*)d_in[8];

    unsigned char* ws = (unsigned char*)d_ws;
    u16*  xb    = (u16*)ws;                          // 38,400,000 B
    u16*  w1t   = (u16*)(ws + 38400000);             //  1,105,920 B (27*20480*2)
    u16*  w2t   = (u16*)(ws + 39505920);             //  1,327,104 B (54*12288*2)
    u16*  h2    = (u16*)(ws + 40833024);             // 38,400,000 B
    float* part = (float*)(ws + 79233024);           //  2,400,768 B
    float* ss1  = (float*)(ws + 81633792);           //      1,536 B
    float* ss2  = (float*)(ws + 81635328);           //        768 B
    float* zbuf = (float*)(ws + 81636096);           //        256 B
    int*  lsrcG = (int*)(ws + 81636352);             // 21,606,912 B

    u16* h = (u16*)d_out;         // reuse d_out (76.8MB) as [N][192] bf16

    prep_kernel<<<19236, 256, 0, stream>>>(x, W1, W2, xb, w1t, w2t, zbuf);
    lsrc_kernel<<<dim3(782, 27), 256, 0, stream>>>(idx, mask, lsrcG);

    // conv1: COUT=192, 2m x 4n waves (FM=4, FN=3), K=96 per offset
    conv_mfma<192, 4, 1><<<NBLK, 512, 0, stream>>>(xb, lsrcG, w1t, zbuf, h, part);
    bn_statsB<192><<<192, 256, 0, stream>>>(part, g1, b1, ss1);
    bn_apply_relu<192><<<18750, 256, 0, stream>>>(h, ss1);

    // conv2: COUT=96, 4m x 2n waves (FM=2, FN=3), K=192 in two 96-phases
    conv_mfma<96, 2, 2><<<NBLK, 512, 0, stream>>>(h, lsrcG, w2t, zbuf, h2, part);
    bn_statsB<96><<<96, 256, 0, stream>>>(part, g2, b2, ss2);
    final_kernel<<<9375, 256, 0, stream>>>(h2, x, ss2, (float*)d_out);
}